// Round 9
// baseline (135.533 us; speedup 1.0000x reference)
//
#include <hip/hip_runtime.h>
#include <hip/hip_bf16.h>

// Problem constants
#define BB 2
#define FDIM 2048
#define FH 64
#define FW 128
#define NPIX (FH*FW)        // 8192 pixels per (dom,b)
#define NC 19
#define SH 512
#define SW 1024

#define KS 4                // pixel splits per (d,b) plane
#define PXS (NPIX/KS)       // 2048 pixels per block (512 per wave)

// Workspace layout (bytes). psq+cnt+sum zeroed each launch (atomic accum).
#define OFF_PSQ   0                         // float psq[8][2][19]     = 1216 B (XCD partials)
#define OFF_CNT   1216                      // uint  cnt[2][19]        = 152 B
#define OFF_SUM   1408                      // float sum[2][19][2048]  = 311296 B
#define ZERO_BYTES 312704
#define OFF_LAB   312704                    // uchar labels[2][2][8192]= 32768 B
#define OFF_CENT  345472                    // float cent[19][2048]    = 155648 B
#define OFF_DOTS  501120                    // float dots[57]
#define OFF_ROW   501348                    // float row[19]

typedef __attribute__((ext_vector_type(8))) short short8v;   // 8 bf16 (4 VGPRs)
typedef __attribute__((ext_vector_type(4))) float f32x4;     // MFMA C/D
typedef __attribute__((ext_vector_type(4))) float f4v;       // NT-loadable float4

__device__ inline short f32_to_bf16_bits(float x) {
  __hip_bfloat16 h = __float2bfloat16(x);
  return *reinterpret_cast<short*>(&h);
}
__device__ inline float bf16_bits_to_f32(short s) {
  unsigned u = ((unsigned)s & 0xFFFFu) << 16;
  return __uint_as_float(u);
}

// ---------------------------------------------------------------------------
// Kernel 1: labels via align_corners bilinear downsample + argmax over C.
// 4 lanes per output pixel, shfl_xor argmax merge, first-max tie-break.
// Replicates jnp.linspace f32 arithmetic / mul-add association exactly.
// ---------------------------------------------------------------------------
__global__ __launch_bounds__(256) void labels_kernel(
    const float* __restrict__ sm_s, const float* __restrict__ sm_t,
    unsigned char* __restrict__ labels, unsigned int* __restrict__ cnt) {
  __shared__ unsigned int lcnt[NC];
  int tid = threadIdx.x;
  if (tid < NC) lcnt[tid] = 0u;
  __syncthreads();

  int g = blockIdx.x * 256 + tid;          // 0..131071
  int pixid = g >> 2;                      // 0..32767
  int sub = g & 3;
  int dom = pixid >> 14;                   // block-uniform
  int rem = pixid & 16383;
  int b   = rem >> 13;
  int pix = rem & (NPIX - 1);
  int oy  = pix >> 7;
  int ox  = pix & (FW - 1);

  const float* sm = dom ? sm_t : sm_s;

  const float step_y = 511.0f / 63.0f;
  const float step_x = 1023.0f / 127.0f;
  float fy = __fmul_rn((float)oy, step_y);
  float fx = __fmul_rn((float)ox, step_x);
  int y0 = (int)floorf(fy); int y1 = min(y0 + 1, SH - 1);
  int x0 = (int)floorf(fx); int x1 = min(x0 + 1, SW - 1);
  float wy = __fsub_rn(fy, (float)y0);
  float wx = __fsub_rn(fx, (float)x0);
  float omwy = __fsub_rn(1.0f, wy);
  float omwx = __fsub_rn(1.0f, wx);

  const float* base = sm + (size_t)b * (NC * SH * SW);
  float best = -1.0f; int bestc = 127;
  for (int c = sub; c < NC; c += 4) {
    const float* p = base + (size_t)c * (SH * SW);
    float v00 = p[y0 * SW + x0];
    float v01 = p[y0 * SW + x1];
    float v10 = p[y1 * SW + x0];
    float v11 = p[y1 * SW + x1];
    float r0  = __fadd_rn(__fmul_rn(v00, omwy), __fmul_rn(v10, wy));
    float r1  = __fadd_rn(__fmul_rn(v01, omwy), __fmul_rn(v11, wy));
    float val = __fadd_rn(__fmul_rn(r0, omwx), __fmul_rn(r1, wx));
    if (val > best) { best = val; bestc = c; }
  }
#pragma unroll
  for (int off = 1; off <= 2; off <<= 1) {
    float ov = __shfl_xor(best, off, 64);
    int   oc = __shfl_xor(bestc, off, 64);
    if (ov > best || (ov == best && oc < bestc)) { best = ov; bestc = oc; }
  }
  if (sub == 0) {
    labels[pixid] = (unsigned char)bestc;
    atomicAdd(&lcnt[bestc], 1u);
  }
  __syncthreads();
  if (tid < NC) atomicAdd(&cnt[dom * NC + tid], lcnt[tid]);
}

// ---------------------------------------------------------------------------
// Kernel 2 (hot): segment-sum as MFMA matmul, wave-private pipelines.
// R9 change: feature loads are NON-TEMPORAL (zero-reuse stream; bypass
// cache allocation -> stream from HBM instead of the L3-hit service path
// that pinned R6/R7/R8 at ~2.6 TB/s delivered). Labels stay cached
// (reused 128x). Everything else identical to R8 for clean attribution.
// ---------------------------------------------------------------------------
__global__ __launch_bounds__(256, 8) void segsum_kernel(
    const float* __restrict__ feat_s, const float* __restrict__ feat_t,
    const unsigned char* __restrict__ labels,
    float* __restrict__ sum, float* __restrict__ psq) {
  __shared__ unsigned short Abuf[4][2][16][64];   // 4 waves x dbuf x 2KB = 16KB

  int tid = threadIdx.x;
  int wv = tid >> 6, l = tid & 63;
  int m16 = l & 15, grp = l >> 4;
  int lrow = l >> 4;                       // sub-row 0..3 for staging
  int lpx  = (l & 15) * 4;                 // px offset 0..60 for staging

  // bid = (d*128 + strip) + 256*(ks*2 + b): colliders share bid%8 -> one XCD
  int low = blockIdx.x & 255;
  int hi  = blockIdx.x >> 8;               // 0..7
  int d = low >> 7, strip = low & 127;
  int b = hi & 1, ks = hi >> 1;

  const float* feat = d ? feat_t : feat_s;
  int px0 = ks * PXS + wv * 512;           // wave-private 512-px chunk
  const float* fbase = feat + ((size_t)(b * FDIM + strip * 16)) * NPIX + px0;
  const unsigned char* labp = labels + (d * 2 + b) * NPIX + px0;

  unsigned short (*mybuf)[16][64] = Abuf[wv];    // [2][16][64]

  f32x4 accS0 = {0.f,0.f,0.f,0.f}, accS1 = {0.f,0.f,0.f,0.f};
  f32x4 accQ0 = {0.f,0.f,0.f,0.f}, accQ1 = {0.f,0.f,0.f,0.f};

  f4v ld[4];

#define LOADW(W)                                                              \
  _Pragma("unroll") for (int r = 0; r < 4; ++r)                               \
    ld[r] = __builtin_nontemporal_load(                                       \
        (const f4v*)(fbase + (size_t)(r * 4 + lrow) * NPIX + (W) * 64 + lpx));

#define WRITEW(CUR)                                                           \
  _Pragma("unroll") for (int r = 0; r < 4; ++r) {                             \
    int row = r * 4 + lrow;                                                   \
    unsigned u0 = ((unsigned)(unsigned short)f32_to_bf16_bits(ld[r].x)) |     \
                  (((unsigned)(unsigned short)f32_to_bf16_bits(ld[r].y)) << 16);\
    unsigned u1 = ((unsigned)(unsigned short)f32_to_bf16_bits(ld[r].z)) |     \
                  (((unsigned)(unsigned short)f32_to_bf16_bits(ld[r].w)) << 16);\
    int wbyte = (row * 128 + lpx * 2) ^ ((row & 7) << 4);                     \
    *(uint2*)((char*)&mybuf[CUR][0][0] + wbyte) = make_uint2(u0, u1);         \
  }

  // prologue: window 0
  LOADW(0);
  WRITEW(0);

#pragma unroll 2
  for (int w = 0; w < 8; ++w) {
    int cur = w & 1;
    if (w < 7) { LOADW(w + 1); }           // issue early; write after compute
#pragma unroll
    for (int t = 0; t < 2; ++t) {
      int rbyte = (m16 * 128 + t * 64 + grp * 16) ^ ((m16 & 7) << 4);
      short8v a = *(const short8v*)((const char*)&mybuf[cur][0][0] + rbyte);
      short8v a2;
#pragma unroll
      for (int j = 0; j < 8; ++j) {
        float x = bf16_bits_to_f32(a[j]);
        a2[j] = f32_to_bf16_bits(x * x);
      }
      uint2 lw = *(const uint2*)(labp + w * 64 + t * 32 + grp * 8);
      short8v b0, b1;
#pragma unroll
      for (int j = 0; j < 8; ++j) {
        unsigned lab = ((j < 4 ? lw.x : lw.y) >> ((j & 3) * 8)) & 0xFFu;
        b0[j] = (lab == (unsigned)m16)        ? (short)0x3F80 : (short)0;
        b1[j] = (lab == (unsigned)(m16 + 16)) ? (short)0x3F80 : (short)0;
      }
      accS0 = __builtin_amdgcn_mfma_f32_16x16x32_bf16(a,  b0, accS0, 0, 0, 0);
      accS1 = __builtin_amdgcn_mfma_f32_16x16x32_bf16(a,  b1, accS1, 0, 0, 0);
      accQ0 = __builtin_amdgcn_mfma_f32_16x16x32_bf16(a2, b0, accQ0, 0, 0, 0);
      accQ1 = __builtin_amdgcn_mfma_f32_16x16x32_bf16(a2, b1, accQ1, 0, 0, 0);
    }
    if (w < 7) { WRITEW(cur ^ 1); }
  }
#undef LOADW
#undef WRITEW

  // ---- epilogue: barrier (Sred aliases Abuf), merge 4 waves, XCD-local atomics
  __syncthreads();
  float* Sred = (float*)&Abuf[0][0][0][0];   // [4][19][16] = 4864 B
  float* Qred = Sred + 4 * 19 * 16;          // [4][19]

  int c0 = l & 15, frb = (l >> 4) * 4;       // C/D: col=class, row=(l>>4)*4+reg
  *(f32x4*)&Sred[(wv * 19 + c0) * 16 + frb] = accS0;
  if (c0 < 3) *(f32x4*)&Sred[(wv * 19 + 16 + c0) * 16 + frb] = accS1;

  float q0 = accQ0[0] + accQ0[1] + accQ0[2] + accQ0[3];
  float q1 = accQ1[0] + accQ1[1] + accQ1[2] + accQ1[3];
  q0 += __shfl_xor(q0, 16, 64); q0 += __shfl_xor(q0, 32, 64);
  q1 += __shfl_xor(q1, 16, 64); q1 += __shfl_xor(q1, 32, 64);
  if (l < 16) Qred[wv * 19 + l] = q0;
  if (l < 3)  Qred[wv * 19 + 16 + l] = q1;
  __syncthreads();

  for (int t = tid; t < NC * 16; t += 256) {
    int c = t >> 4, fr = t & 15;
    float sv = Sred[(0 * 19 + c) * 16 + fr] + Sred[(1 * 19 + c) * 16 + fr] +
               Sred[(2 * 19 + c) * 16 + fr] + Sred[(3 * 19 + c) * 16 + fr];
    unsafeAtomicAdd(&sum[((size_t)d * NC + c) * FDIM + strip * 16 + fr], sv);
  }
  if (tid < NC) {
    float qv = Qred[tid] + Qred[19 + tid] + Qred[38 + tid] + Qred[57 + tid];
    unsafeAtomicAdd(&psq[(blockIdx.x & 7) * (2 * NC) + d * NC + tid], qv);
  }
}

// Block reduction helper (256 threads)
__device__ inline float block_reduce(float v, float* red, int tid) {
  red[tid] = v; __syncthreads();
  for (int s = 128; s > 0; s >>= 1) {
    if (tid < s) red[tid] += red[tid + s];
    __syncthreads();
  }
  float r = red[0];
  __syncthreads();
  return r;
}

// ---------------------------------------------------------------------------
// Kernel 3a: centroids + per-class dots.
// ---------------------------------------------------------------------------
__global__ __launch_bounds__(256) void centroid_kernel(
    const float* __restrict__ sum, const unsigned int* __restrict__ cnt,
    float* __restrict__ cent, float* __restrict__ dots) {
  __shared__ float red[256];
  int c = blockIdx.x;
  int tid = threadIdx.x;
  float cs = (float)cnt[c];
  float ct = (float)cnt[NC + c];
  float denom = fmaxf(cs + ct, 1.0f);
  float ds = 0.f, dt = 0.f, cc = 0.f;
  for (int f = tid; f < FDIM; f += 256) {
    float ssv = sum[(size_t)c * FDIM + f];
    float stv = sum[(size_t)(NC + c) * FDIM + f];
    float cf = (ssv + stv) / denom;
    cent[(size_t)c * FDIM + f] = cf;
    ds += cf * ssv; dt += cf * stv; cc += cf * cf;
  }
  float rds = block_reduce(ds, red, tid);
  float rdt = block_reduce(dt, red, tid);
  float rcc = block_reduce(cc, red, tid);
  if (tid == 0) {
    dots[c] = rds;
    dots[NC + c] = rdt;
    dots[2 * NC + c] = rcc;
  }
}

// ---------------------------------------------------------------------------
// Kernel 3b: row[i] = sum_{j != i, seen i&j} sum_f (c_i - c_j)^2
// ---------------------------------------------------------------------------
__global__ __launch_bounds__(256) void pair_kernel(
    const float* __restrict__ cent, const unsigned int* __restrict__ cnt,
    float* __restrict__ row) {
  __shared__ float red[256];
  int i = blockIdx.x;
  int tid = threadIdx.x;
  bool seen_i = (cnt[i] + cnt[NC + i]) > 0u;
  float acc = 0.f;
  if (seen_i) {
    for (int j = 0; j < NC; ++j) {
      if (j == i) continue;
      if ((cnt[j] + cnt[NC + j]) == 0u) continue;
      for (int f = tid; f < FDIM; f += 256) {
        float dd = cent[(size_t)i * FDIM + f] - cent[(size_t)j * FDIM + f];
        acc += dd * dd;
      }
    }
  }
  float r = block_reduce(acc, red, tid);
  if (tid == 0) row[i] = r;
}

// ---------------------------------------------------------------------------
// Kernel 3c: fold psq partials, assemble the 3 outputs (p == 2).
// One wave, lane c handles class c; ballot/popc + shfl_down trees.
// ---------------------------------------------------------------------------
__global__ void final_kernel(
    const unsigned int* __restrict__ cnt, const float* __restrict__ psq,
    const float* __restrict__ dots, const float* __restrict__ row,
    float* __restrict__ out) {
  int l = threadIdx.x;                      // one wave of 64
  const float fdim = (float)FDIM;
  bool isC = l < NC;
  int c = isC ? l : 0;

  float cs = 0.f, ct = 0.f, qs = 0.f, qt = 0.f;
  float d_s = 0.f, d_t = 0.f, cc = 0.f, rw = 0.f;
  if (isC) {
    cs = (float)cnt[c]; ct = (float)cnt[NC + c];
#pragma unroll
    for (int x = 0; x < 8; ++x) {           // 16 independent loads, all in flight
      qs += psq[x * (2 * NC) + c];
      qt += psq[x * (2 * NC) + NC + c];
    }
    d_s = dots[c]; d_t = dots[NC + c]; cc = dots[2 * NC + c];
    rw = row[c];
  }
  bool seen = isC && (cs + ct > 0.f);
  float nseenf = (float)__popcll(__ballot(seen));
  float nvs    = (float)__popcll(__ballot(isC && cs > 0.f));
  float nvt    = (float)__popcll(__ballot(isC && ct > 0.f));

  float fs = 0.f, ft = 0.f, cd = 0.f;
  if (isC && cs > 0.f) {
    float ssq = fmaxf(qs - 2.0f * d_s + cs * cc, 0.f);
    fs = sqrtf(ssq) / (cs * fdim);
  }
  if (isC && ct > 0.f) {
    float ssq = fmaxf(qt - 2.0f * d_t + ct * cc, 0.f);
    ft = sqrtf(ssq) / (ct * fdim);
  }
  if (seen) cd = sqrtf(rw) / ((nseenf - 1.0f) * fdim);

#pragma unroll
  for (int off = 32; off > 0; off >>= 1) {
    fs += __shfl_down(fs, off, 64);
    ft += __shfl_down(ft, off, 64);
    cd += __shfl_down(cd, off, 64);
  }
  if (l == 0) {
    out[0] = cd / nseenf;
    out[1] = fs / nvs;
    out[2] = ft / nvt;
  }
}

extern "C" void kernel_launch(void* const* d_in, const int* in_sizes, int n_in,
                              void* d_out, int out_size, void* d_ws, size_t ws_size,
                              hipStream_t stream) {
  const float* sfeat = (const float*)d_in[0];
  const float* ssm   = (const float*)d_in[1];
  const float* tfeat = (const float*)d_in[2];
  const float* tsm   = (const float*)d_in[3];
  float* out = (float*)d_out;

  char* ws = (char*)d_ws;
  float*         psq    = (float*)(ws + OFF_PSQ);
  unsigned int*  cnt    = (unsigned int*)(ws + OFF_CNT);
  float*         sum    = (float*)(ws + OFF_SUM);
  unsigned char* labels = (unsigned char*)(ws + OFF_LAB);
  float*         cent   = (float*)(ws + OFF_CENT);
  float*         dots   = (float*)(ws + OFF_DOTS);
  float*         row    = (float*)(ws + OFF_ROW);

  // zero psq+cnt+sum (atomic accumulators; graph replays need re-zeroing)
  hipMemsetAsync(ws, 0, ZERO_BYTES, stream);

  labels_kernel  <<<512,  256, 0, stream>>>(ssm, tsm, labels, cnt);
  segsum_kernel  <<<2048, 256, 0, stream>>>(sfeat, tfeat, labels, sum, psq);
  centroid_kernel<<<NC,   256, 0, stream>>>(sum, cnt, cent, dots);
  pair_kernel    <<<NC,   256, 0, stream>>>(cent, cnt, row);
  final_kernel   <<<1,    64,  0, stream>>>(cnt, psq, dots, row, out);
}